// Round 1
// baseline (3609.151 us; speedup 1.0000x reference)
//
#include <hip/hip_runtime.h>
#include <hip/hip_bf16.h>
#include <math.h>

#define HEADS 4
#define HID 64
#define OUTD 7

__device__ __forceinline__ float gelu_exact(float x) {
    return 0.5f * x * (1.0f + erff(x * 0.70710678118654752f));
}

// ---------------- CSR build ----------------

__global__ void hist_kernel(const int* __restrict__ dst, int* __restrict__ cnt, int E) {
    for (int e = blockIdx.x * blockDim.x + threadIdx.x; e < E; e += gridDim.x * blockDim.x)
        atomicAdd(&cnt[dst[e]], 1);
}

__global__ __launch_bounds__(256) void scan1_kernel(const int* __restrict__ cnt,
                                                    int* __restrict__ rowptr,
                                                    int* __restrict__ bsum, int Nn) {
    __shared__ int sums[256];
    int t = threadIdx.x;
    int base = blockIdx.x * 2048 + t * 8;
    int orig[8];
    int run = 0;
#pragma unroll
    for (int i = 0; i < 8; i++) {
        orig[i] = (base + i < Nn) ? cnt[base + i] : 0;
        run += orig[i];
    }
    sums[t] = run;
    __syncthreads();
    for (int off = 1; off < 256; off <<= 1) {
        int y = (t >= off) ? sums[t - off] : 0;
        __syncthreads();
        sums[t] += y;
        __syncthreads();
    }
    int excl = sums[t] - run;
    if (t == 255) bsum[blockIdx.x] = sums[255];
    int e = excl;
#pragma unroll
    for (int i = 0; i < 8; i++) {
        if (base + i < Nn) rowptr[base + i] = e;
        e += orig[i];
    }
}

__global__ void scan2_kernel(int* __restrict__ bsum, int* __restrict__ rowptr, int nb, int Nn) {
    if (blockIdx.x == 0 && threadIdx.x == 0) {
        int run = 0;
        for (int i = 0; i < nb; i++) {
            int t = bsum[i];
            bsum[i] = run;
            run += t;
        }
        rowptr[Nn] = run;
    }
}

__global__ void scan3_kernel(int* __restrict__ rowptr, const int* __restrict__ bsum, int Nn) {
    int i = blockIdx.x * blockDim.x + threadIdx.x;
    if (i < Nn) rowptr[i] += bsum[i >> 11];
}

__global__ void scatter_kernel(const int* __restrict__ dst, const int* __restrict__ rowptr,
                               int* __restrict__ cnt, int* __restrict__ eidx, int E) {
    for (int e = blockIdx.x * blockDim.x + threadIdx.x; e < E; e += gridDim.x * blockDim.x) {
        int d = dst[e];
        int p = rowptr[d] + atomicAdd(&cnt[d], 1);
        eidx[p] = e;
    }
}

// ---------------- GEMM ----------------
// MODE 0: X[N,64]  @ Wcat[64,256] (W per-head [4][64][64]) + b[256] -> Z[N,256]
// MODE 1: X[N,256] @ W[256,64] + b[64]                             -> Z[N,64]
// MODE 2: X[N,64]  @ Wo per-head [4][64][7] + bo[4][7]             -> Z[N,32] (pad 8/head)

template <int MODE>
__global__ __launch_bounds__(256) void gemm_kernel(const float* __restrict__ X,
                                                   const float* __restrict__ Wt,
                                                   const float* __restrict__ Bt,
                                                   float* __restrict__ Z, int Nn) {
    constexpr int K = (MODE == 1) ? 256 : 64;
    constexpr int M = (MODE == 0) ? 256 : (MODE == 1 ? 64 : 32);
    constexpr int MC = (MODE == 2) ? 32 : 64;
    constexpr int CPT = MC / 8;  // cols per thread: 8 or 4
    constexpr int NMC = M / MC;
    constexpr int NKC = K / 64;
    constexpr int WSTR = MC + 4;
    __shared__ float xs[64][72];
    __shared__ float ws_[64][WSTR];
    int tid = threadIdx.x;
    int rg = tid >> 3, cg = tid & 7;  // rg: 0..31 -> rows rg*2, rg*2+1
    int n0 = blockIdx.x * 64;

    for (int mc = 0; mc < NMC; ++mc) {
        float acc0[CPT] = {}, acc1[CPT] = {};
        for (int kc = 0; kc < NKC; ++kc) {
            __syncthreads();
            {  // load X chunk: 64 rows x 64 k
                int r = tid >> 2;
                int kb = (tid & 3) * 16;
                int nr = n0 + r;
                int nrc = (nr < Nn) ? nr : (Nn - 1);
                const float* xp = X + (size_t)nrc * K + kc * 64 + kb;
                float4 v0 = ((const float4*)xp)[0];
                float4 v1 = ((const float4*)xp)[1];
                float4 v2 = ((const float4*)xp)[2];
                float4 v3 = ((const float4*)xp)[3];
                *(float4*)&xs[r][kb + 0] = v0;
                *(float4*)&xs[r][kb + 4] = v1;
                *(float4*)&xs[r][kb + 8] = v2;
                *(float4*)&xs[r][kb + 12] = v3;
            }
            if (MODE != 2) {  // load W chunk (contiguous 4096-float block)
                const float* wp = Wt + (MODE == 0 ? mc * 4096 : kc * 4096);
#pragma unroll
                for (int rep = 0; rep < 4; ++rep) {
                    int flat = rep * 1024 + tid * 4;
                    int k = flat >> 6, m = flat & 63;
                    float4 w = *(const float4*)(wp + flat);
                    *(float4*)&ws_[k][m] = w;
                }
            } else {
                for (int idx = tid; idx < 64 * 32; idx += 256) {
                    int k = idx >> 5, mm = idx & 31, h = mm >> 3, jj = mm & 7;
                    ws_[k][mm] = (jj < 7) ? Wt[h * 448 + k * 7 + jj] : 0.f;
                }
            }
            __syncthreads();
            int r0 = rg * 2, r1 = r0 + 1;
#pragma unroll
            for (int k = 0; k < 64; k++) {
                float x0 = xs[r0][k], x1 = xs[r1][k];
#pragma unroll
                for (int j = 0; j < CPT; j++) {
                    float w = ws_[k][cg * CPT + j];
                    acc0[j] = fmaf(x0, w, acc0[j]);
                    acc1[j] = fmaf(x1, w, acc1[j]);
                }
            }
        }
        // epilogue
        int nrow0 = n0 + rg * 2, nrow1 = nrow0 + 1;
        if (MODE != 2) {
            int mbase = mc * MC + cg * CPT;
            float4 bv0 = *(const float4*)(Bt + mbase);
            float4 bv1 = *(const float4*)(Bt + mbase + 4);
            if (nrow0 < Nn) {
                float4 s0 = {acc0[0] + bv0.x, acc0[1] + bv0.y, acc0[2] + bv0.z, acc0[3] + bv0.w};
                float4 s1 = {acc0[4] + bv1.x, acc0[5] + bv1.y, acc0[6] + bv1.z, acc0[7] + bv1.w};
                *(float4*)(Z + (size_t)nrow0 * M + mbase) = s0;
                *(float4*)(Z + (size_t)nrow0 * M + mbase + 4) = s1;
            }
            if (nrow1 < Nn) {
                float4 s0 = {acc1[0] + bv0.x, acc1[1] + bv0.y, acc1[2] + bv0.z, acc1[3] + bv0.w};
                float4 s1 = {acc1[4] + bv1.x, acc1[5] + bv1.y, acc1[6] + bv1.z, acc1[7] + bv1.w};
                *(float4*)(Z + (size_t)nrow1 * M + mbase) = s0;
                *(float4*)(Z + (size_t)nrow1 * M + mbase + 4) = s1;
            }
        } else {
#pragma unroll
            for (int j = 0; j < CPT; j++) {
                int mm = cg * CPT + j, h = mm >> 3, jj = mm & 7;
                float bv = (jj < 7) ? Bt[h * 7 + jj] : 0.f;
                if (nrow0 < Nn) Z[(size_t)nrow0 * 32 + mm] = (jj < 7) ? acc0[j] + bv : 0.f;
                if (nrow1 < Nn) Z[(size_t)nrow1 * 32 + mm] = (jj < 7) ? acc1[j] + bv : 0.f;
            }
        }
    }
}

// ---------------- per-node attention scalars ----------------
// SL[h][n] = z_row . a[h][:D] ; SR[h][n] = z_row . a[h][D:]

template <int NH, int D, int DP>
__global__ __launch_bounds__(256) void slr_kernel(const float* __restrict__ Z,
                                                  const float* __restrict__ A,
                                                  float* __restrict__ SL, float* __restrict__ SR,
                                                  int Nn) {
    int gw = (blockIdx.x * blockDim.x + threadIdx.x) >> 6;
    int lane = threadIdx.x & 63;
    int total = Nn * NH;
    if (gw >= total) return;
    int n = gw / NH, h = gw % NH;
    float v = 0.f, al = 0.f, ar = 0.f;
    if (lane < D) {
        v = Z[(size_t)n * (NH * DP) + h * DP + lane];
        al = A[h * 2 * D + lane];
        ar = A[h * 2 * D + D + lane];
    }
    float sl = v * al, sr = v * ar;
#pragma unroll
    for (int off = 32; off; off >>= 1) {
        sl += __shfl_xor(sl, off);
        sr += __shfl_xor(sr, off);
    }
    if (lane == 0) {
        SL[(size_t)h * Nn + n] = sl;
        SR[(size_t)h * Nn + n] = sr;
    }
}

// ---------------- aggregation: one wave per (node, head) ----------------

template <int NH, int D, int DP>
__global__ __launch_bounds__(256) void aggregate_kernel(
    const float* __restrict__ Z, const float* __restrict__ SL, const float* __restrict__ SR,
    const int* __restrict__ rowptr, const int* __restrict__ eidx, const int* __restrict__ srcv,
    float* __restrict__ Hout, int Nn) {
    constexpr int ZS = NH * DP;
    int gw = (blockIdx.x * blockDim.x + threadIdx.x) >> 6;
    int lane = threadIdx.x & 63;
    int total = Nn * NH;
    if (gw >= total) return;
    int n = gw / NH, h = gw % NH;
    int s0 = rowptr[n], s1 = rowptr[n + 1];
    const float* sl = SL + (size_t)h * Nn;
    float srn = SR[(size_t)h * Nn + n];

    if (s1 == s0) {
        if (D == 64)
            Hout[(size_t)n * ZS + h * DP + lane] = 0.f;
        else if (lane < 8)
            Hout[(size_t)n * ZS + h * DP + lane] = 0.f;
        return;
    }
    // pass A: segment max
    float m = -INFINITY;
    for (int base = s0; base < s1; base += 64) {
        int j = base + lane;
        if (j < s1) {
            int sv = srcv[eidx[j]];
            m = fmaxf(m, gelu_exact(sl[sv] + srn));
        }
    }
#pragma unroll
    for (int off = 32; off; off >>= 1) m = fmaxf(m, __shfl_xor(m, off));

    // pass B: exp, denom, weighted accumulate
    float denom = 0.f;
    float hacc = 0.f;
    for (int base = s0; base < s1; base += 64) {
        int j = base + lane;
        float ex = 0.f;
        int sv = 0;
        if (j < s1) {
            sv = srcv[eidx[j]];
            ex = __expf(gelu_exact(sl[sv] + srn) - m);
        }
        denom += ex;
        int cs = min(64, s1 - base);
        if (D == 64) {
            for (int jj = 0; jj < cs; ++jj) {
                float exv = __shfl(ex, jj);
                int s = __shfl(sv, jj);
                hacc = fmaf(exv, Z[(size_t)s * ZS + h * DP + lane], hacc);
            }
        } else {
            int eo = lane >> 3, k = lane & 7;
            for (int jj = 0; jj < cs; jj += 8) {
                int edge = jj + eo;
                float exv = __shfl(ex, edge);
                int s = __shfl(sv, edge);
                if (k < 7) hacc = fmaf(exv, Z[(size_t)s * ZS + h * DP + k], hacc);
            }
        }
    }
#pragma unroll
    for (int off = 32; off; off >>= 1) denom += __shfl_xor(denom, off);
    if (D != 64) {
        hacc += __shfl_xor(hacc, 8);
        hacc += __shfl_xor(hacc, 16);
        hacc += __shfl_xor(hacc, 32);
    }
    float inv = 1.f / denom;
    if (D == 64)
        Hout[(size_t)n * ZS + h * DP + lane] = hacc * inv;
    else if (lane < 8)
        Hout[(size_t)n * ZS + h * DP + lane] = hacc * inv;  // lane 7: hacc==0 -> pad 0
}

// ---------------- mean-over-heads + linear + softmax ----------------

__global__ void finalize_kernel(const float* __restrict__ Hs, const float* __restrict__ LW,
                                const float* __restrict__ LB, float* __restrict__ out, int Nn) {
    int n = blockIdx.x * blockDim.x + threadIdx.x;
    if (n >= Nn) return;
    float mean[7];
#pragma unroll
    for (int k = 0; k < 7; k++)
        mean[k] = 0.25f * (Hs[(size_t)n * 32 + k] + Hs[(size_t)n * 32 + 8 + k] +
                           Hs[(size_t)n * 32 + 16 + k] + Hs[(size_t)n * 32 + 24 + k]);
    float lg[7];
#pragma unroll
    for (int o = 0; o < 7; o++) {
        float acc = LB[o];
#pragma unroll
        for (int k = 0; k < 7; k++) acc = fmaf(mean[k], LW[k * 7 + o], acc);
        lg[o] = acc;
    }
    float mx = lg[0];
#pragma unroll
    for (int o = 1; o < 7; o++) mx = fmaxf(mx, lg[o]);
    float s = 0.f;
#pragma unroll
    for (int o = 0; o < 7; o++) {
        lg[o] = __expf(lg[o] - mx);
        s += lg[o];
    }
    float inv = 1.f / s;
#pragma unroll
    for (int o = 0; o < 7; o++) out[(size_t)n * 7 + o] = lg[o] * inv;
}

// ---------------- launch ----------------

extern "C" void kernel_launch(void* const* d_in, const int* in_sizes, int n_in,
                              void* d_out, int out_size, void* d_ws, size_t ws_size,
                              hipStream_t stream) {
    const float* feature = (const float*)d_in[0];
    const int* src = (const int*)d_in[1];
    const int* dst = (const int*)d_in[2];
    const float* W0 = (const float*)d_in[3];
    const float* b0 = (const float*)d_in[4];
    const float* a0 = (const float*)d_in[5];
    const float* W0h = (const float*)d_in[6];
    const float* b0h = (const float*)d_in[7];
    const float* a0h = (const float*)d_in[8];
    const float* W1 = (const float*)d_in[9];
    const float* b1 = (const float*)d_in[10];
    const float* a1 = (const float*)d_in[11];
    const float* W1h = (const float*)d_in[12];
    const float* b1h = (const float*)d_in[13];
    const float* a1h = (const float*)d_in[14];
    const float* Wo = (const float*)d_in[15];
    const float* bo = (const float*)d_in[16];
    const float* ao = (const float*)d_in[17];
    const float* linW = (const float*)d_in[18];
    const float* linb = (const float*)d_in[19];
    const int N = in_sizes[0] / 64;
    const int E = in_sizes[1];
    float* out = (float*)d_out;

    char* ws = (char*)d_ws;
    size_t off = 0;
    auto alloc = [&](size_t bytes) {
        void* p = ws + off;
        off += (bytes + 255) & ~(size_t)255;
        return p;
    };
    int* cnt = (int*)alloc((size_t)N * 4);
    int* rowptr = (int*)alloc(((size_t)N + 1) * 4);
    int* bsum = (int*)alloc(256 * 4);
    int* eidx = (int*)alloc((size_t)E * 4);
    float* zbuf = (float*)alloc((size_t)N * 256 * 4);
    float* hbuf = (float*)alloc((size_t)N * 256 * 4);
    float* fbuf = (float*)alloc((size_t)N * 64 * 4);
    float* slb = (float*)alloc((size_t)N * 4 * 4);
    float* srb = (float*)alloc((size_t)N * 4 * 4);
    float* houts = fbuf;  // safe alias: f2 dead after out-GEMM reads it

    // --- CSR by dst (reused by all 5 aggregation stages) ---
    hipMemsetAsync(cnt, 0, (size_t)N * 4, stream);
    hist_kernel<<<2048, 256, 0, stream>>>(dst, cnt, E);
    int nb = (N + 2047) / 2048;
    scan1_kernel<<<nb, 256, 0, stream>>>(cnt, rowptr, bsum, N);
    scan2_kernel<<<1, 32, 0, stream>>>(bsum, rowptr, nb, N);
    scan3_kernel<<<(N + 255) / 256, 256, 0, stream>>>(rowptr, bsum, N);
    hipMemsetAsync(cnt, 0, (size_t)N * 4, stream);
    scatter_kernel<<<2048, 256, 0, stream>>>(dst, rowptr, cnt, eidx, E);

    int gemm_blocks = (N + 63) / 64;
    int blk4 = (N * HEADS + 3) / 4;  // waves = N*4
    int blk1 = (N + 3) / 4;          // waves = N

    // --- layer 0 (4 heads, concat) ---
    gemm_kernel<0><<<gemm_blocks, 256, 0, stream>>>(feature, W0, b0, zbuf, N);
    slr_kernel<4, 64, 64><<<blk4, 256, 0, stream>>>(zbuf, a0, slb, srb, N);
    aggregate_kernel<4, 64, 64><<<blk4, 256, 0, stream>>>(zbuf, slb, srb, rowptr, eidx, src, hbuf, N);
    // --- layer 0 head_linear ---
    gemm_kernel<1><<<gemm_blocks, 256, 0, stream>>>(hbuf, W0h, b0h, zbuf, N);
    slr_kernel<1, 64, 64><<<blk1, 256, 0, stream>>>(zbuf, a0h, slb, srb, N);
    aggregate_kernel<1, 64, 64><<<blk1, 256, 0, stream>>>(zbuf, slb, srb, rowptr, eidx, src, fbuf, N);
    // --- layer 1 (4 heads, concat) ---
    gemm_kernel<0><<<gemm_blocks, 256, 0, stream>>>(fbuf, W1, b1, zbuf, N);
    slr_kernel<4, 64, 64><<<blk4, 256, 0, stream>>>(zbuf, a1, slb, srb, N);
    aggregate_kernel<4, 64, 64><<<blk4, 256, 0, stream>>>(zbuf, slb, srb, rowptr, eidx, src, hbuf, N);
    // --- layer 1 head_linear ---
    gemm_kernel<1><<<gemm_blocks, 256, 0, stream>>>(hbuf, W1h, b1h, zbuf, N);
    slr_kernel<1, 64, 64><<<blk1, 256, 0, stream>>>(zbuf, a1h, slb, srb, N);
    aggregate_kernel<1, 64, 64><<<blk1, 256, 0, stream>>>(zbuf, slb, srb, rowptr, eidx, src, fbuf, N);
    // --- out layer (4 heads, mean) ---
    gemm_kernel<2><<<gemm_blocks, 256, 0, stream>>>(fbuf, Wo, bo, zbuf, N);
    slr_kernel<4, 7, 8><<<blk4, 256, 0, stream>>>(zbuf, ao, slb, srb, N);
    aggregate_kernel<4, 7, 8><<<blk4, 256, 0, stream>>>(zbuf, slb, srb, rowptr, eidx, src, houts, N);
    finalize_kernel<<<(N + 255) / 256, 256, 0, stream>>>(houts, linW, linb, out, N);
}